// Round 4
// baseline (356.820 us; speedup 1.0000x reference)
//
#include <hip/hip_runtime.h>
#include <hip/hip_bf16.h>

// ---------------------------------------------------------------------------
// GAT (2 layers) + mean pool + MLP head.
// R2->R3: both GEMMs moved to bf16 MFMA (16x16x32), fragments loaded directly
// from global (no LDS), weights pre-transposed to [col][k] bf16. Gathered x
// cast to bf16 (halves aggx traffic). Attention weights & softmax stay fp32.
// MFMA operand layout (m156/m162): lane l elem j -> k = 16*(j>>2)+4*(l>>4)+(j&3);
// A row = l&15, B col = l&15; D row=(l>>4)*4+reg, col=l&15.
// ---------------------------------------------------------------------------

typedef unsigned short u16;
typedef unsigned int u32;
typedef __attribute__((ext_vector_type(8))) short bf16x8;
typedef __attribute__((ext_vector_type(4))) float f32x4;

#define LRELU(v) ((v) > 0.0f ? (v) : 0.2f * (v))
#define ELU(v)   ((v) > 0.0f ? (v) : expm1f(v))

__device__ __forceinline__ u16 f2bf(float f) {
    union { float f; u32 u; } c; c.f = f;
    u32 u = c.u;
    u32 r = (u + 0x7fffu + ((u >> 16) & 1u)) >> 16;
    return (u16)r;
}

__device__ __forceinline__ bf16x8 ldfrag(const u16* p) {
    ushort4 c0 = *(const ushort4*)(p);
    ushort4 c1 = *(const ushort4*)(p + 16);
    bf16x8 f;
    f[0] = (short)c0.x; f[1] = (short)c0.y; f[2] = (short)c0.z; f[3] = (short)c0.w;
    f[4] = (short)c1.x; f[5] = (short)c1.y; f[6] = (short)c1.z; f[7] = (short)c1.w;
    return f;
}

// ---- casts ----------------------------------------------------------------
__global__ __launch_bounds__(256) void castx_kernel(const float* __restrict__ x,
                                                    u16* __restrict__ xbf, int n4) {
    int i = blockIdx.x * 256 + threadIdx.x;
    if (i >= n4) return;
    float4 v = *(const float4*)(x + (size_t)i * 4);
    ushort4 o;
    o.x = f2bf(v.x); o.y = f2bf(v.y); o.z = f2bf(v.z); o.w = f2bf(v.w);
    *(ushort4*)(xbf + (size_t)i * 4) = o;
}

// W1t[c*128+k] = W1[k*512+c]; W2t[c*512+k] = W2[k*64+c]   (bf16)
__global__ __launch_bounds__(256) void castw_kernel(const float* __restrict__ W1,
                                                    const float* __restrict__ W2,
                                                    u16* __restrict__ W1t,
                                                    u16* __restrict__ W2t) {
    int idx = blockIdx.x * 256 + threadIdx.x;
    if (idx < 512 * 128) {
        int c = idx >> 7, k = idx & 127;
        W1t[idx] = f2bf(W1[(size_t)k * 512 + c]);
    }
    int j = idx - 512 * 128;
    if (j >= 0 && j < 64 * 512) {
        int c = j >> 9, k = j & 511;
        W2t[j] = f2bf(W2[(size_t)k * 64 + c]);
    }
}

// ---- fold W1 with a_src/a_dst: Wa[k][j]; j<4 src head j, j>=4 dst ---------
__global__ __launch_bounds__(256) void wa_kernel(const float* __restrict__ W1,
                                                 const float* __restrict__ a_s,
                                                 const float* __restrict__ a_d,
                                                 float* __restrict__ Wa) {
    int idx = blockIdx.x * 256 + threadIdx.x;   // 0..1023
    int k = idx >> 3, j = idx & 7, h = j & 3;
    const float* a = (j < 4) ? (a_s + h * 128) : (a_d + h * 128);
    const float* wrow = W1 + (size_t)k * 512 + h * 128;
    float s = 0.f;
#pragma unroll 8
    for (int o = 0; o < 128; ++o) s += wrow[o] * a[o];
    Wa[k * 8 + j] = s;
}

// ---- alS1/alD1 = x @ Wa  (one wave per node) ------------------------------
__global__ __launch_bounds__(256) void al12_kernel(const float* __restrict__ x,
                                                   const float* __restrict__ Wa,
                                                   float* __restrict__ alS,
                                                   float* __restrict__ alD, int Nn) {
    int lane = threadIdx.x & 63;
    int wave = threadIdx.x >> 6;
    float4 ls = *(const float4*)(Wa + lane * 8);
    float4 ld = *(const float4*)(Wa + lane * 8 + 4);
    float4 hs = *(const float4*)(Wa + (lane + 64) * 8);
    float4 hd = *(const float4*)(Wa + (lane + 64) * 8 + 4);
    int n = blockIdx.x * 4 + wave;
    if (n >= Nn) return;
    float x0 = x[(size_t)n * 128 + lane];
    float x1 = x[(size_t)n * 128 + lane + 64];
    float r0 = x0 * ls.x + x1 * hs.x;
    float r1 = x0 * ls.y + x1 * hs.y;
    float r2 = x0 * ls.z + x1 * hs.z;
    float r3 = x0 * ls.w + x1 * hs.w;
    float r4 = x0 * ld.x + x1 * hd.x;
    float r5 = x0 * ld.y + x1 * hd.y;
    float r6 = x0 * ld.z + x1 * hd.z;
    float r7 = x0 * ld.w + x1 * hd.w;
#pragma unroll
    for (int off = 32; off; off >>= 1) {
        r0 += __shfl_down(r0, off); r1 += __shfl_down(r1, off);
        r2 += __shfl_down(r2, off); r3 += __shfl_down(r3, off);
        r4 += __shfl_down(r4, off); r5 += __shfl_down(r5, off);
        r6 += __shfl_down(r6, off); r7 += __shfl_down(r7, off);
    }
    if (lane == 0) {
        *(float4*)(alS + (size_t)n * 4) = make_float4(r0, r1, r2, r3);
        *(float4*)(alD + (size_t)n * 4) = make_float4(r4, r5, r6, r7);
    }
}

// ---------------- CSR build ------------------------------------------------
__global__ __launch_bounds__(256) void count_kernel(const int* __restrict__ dst,
                                                    int E, int Nn, int* __restrict__ deg) {
    int e = blockIdx.x * 256 + threadIdx.x;
    if (e >= E + Nn) return;
    int d = (e < E) ? dst[e] : (e - E);
    atomicAdd(&deg[d], 1);
}

__global__ __launch_bounds__(256) void scanA_kernel(const int* __restrict__ deg,
                                                    int* __restrict__ offs,
                                                    int* __restrict__ bsum, int n) {
    __shared__ int sh[256];
    int b = blockIdx.x, t = threadIdx.x;
    int base = b * 2048 + t * 8;
    int v[8]; int s = 0;
#pragma unroll
    for (int j = 0; j < 8; ++j) { int i = base + j; v[j] = (i < n) ? deg[i] : 0; s += v[j]; }
    sh[t] = s;
    __syncthreads();
    for (int off = 1; off < 256; off <<= 1) {
        int u = (t >= off) ? sh[t - off] : 0;
        __syncthreads();
        sh[t] += u;
        __syncthreads();
    }
    int run = sh[t] - s;
    if (t == 255) bsum[b] = sh[255];
#pragma unroll
    for (int j = 0; j < 8; ++j) {
        run += v[j];
        int i = base + j;
        if (i < n) offs[i + 1] = run;
    }
}

__global__ __launch_bounds__(64) void scanB_kernel(int* __restrict__ bsum, int nb) {
    int t = threadIdx.x;
    int v = (t < nb) ? bsum[t] : 0;
#pragma unroll
    for (int off = 1; off < 64; off <<= 1) {
        int u = __shfl_up(v, off);
        if (t >= off) v += u;
    }
    if (t < nb) bsum[t] = v;
}

__global__ __launch_bounds__(256) void scanC_kernel(int* __restrict__ offs,
                                                    const int* __restrict__ bsum, int n) {
    int i = blockIdx.x * 256 + threadIdx.x;
    if (i == 0) offs[0] = 0;
    if (i >= n) return;
    int b = i >> 11;
    if (b > 0) offs[i + 1] += bsum[b - 1];
}

__global__ __launch_bounds__(256) void scatter_kernel(const int* __restrict__ dst,
                                                      int E, int Nn,
                                                      const int* __restrict__ offs,
                                                      int* __restrict__ fill,
                                                      int* __restrict__ perm) {
    int e = blockIdx.x * 256 + threadIdx.x;
    if (e >= E + Nn) return;
    int d = (e < E) ? dst[e] : (e - E);
    int pos = offs[d] + atomicAdd(&fill[d], 1);
    perm[pos] = e;
}

// ---- per-edge exp weights, layer 1 (H=4) ----------------------------------
__global__ __launch_bounds__(256) void edgew1_kernel(const int* __restrict__ src,
                                                     const int* __restrict__ dst,
                                                     int E, int Nn,
                                                     const float* __restrict__ alS,
                                                     const float* __restrict__ alD,
                                                     float* __restrict__ wE) {
    int e = blockIdx.x * 256 + threadIdx.x;
    if (e >= E + Nn) return;
    int s = (e < E) ? src[e] : (e - E);
    int d = (e < E) ? dst[e] : (e - E);
    float4 as = *(const float4*)(alS + (size_t)s * 4);
    float4 ad = *(const float4*)(alD + (size_t)d * 4);
    float4 w;
    float t;
    t = as.x + ad.x; w.x = expf(LRELU(t));
    t = as.y + ad.y; w.y = expf(LRELU(t));
    t = as.z + ad.z; w.z = expf(LRELU(t));
    t = as.w + ad.w; w.w = expf(LRELU(t));
    *(float4*)(wE + (size_t)e * 4) = w;
}

// ---- layer-1 aggregate of bf16 x -> bf16 xagg -----------------------------
__global__ __launch_bounds__(64) void aggx_kernel(const u16* __restrict__ xbf,
                                                  const int* __restrict__ src,
                                                  const int* __restrict__ offs,
                                                  const int* __restrict__ perm,
                                                  const float* __restrict__ wE,
                                                  u16* __restrict__ xagg,
                                                  int E) {
    int n = blockIdx.x;
    int t = threadIdx.x;               // 2 feats per lane
    float a0x = 0.f, a0y = 0.f, a1x = 0.f, a1y = 0.f;
    float a2x = 0.f, a2y = 0.f, a3x = 0.f, a3y = 0.f;
    float ws0 = 0.f, ws1 = 0.f, ws2 = 0.f, ws3 = 0.f;
    int s0 = offs[n], s1 = offs[n + 1];
    for (int i = s0; i < s1; ++i) {
        int eid = perm[i];
        int sn = (eid < E) ? src[eid] : (eid - E);
        float4 w = *(const float4*)(wE + (size_t)eid * 4);   // wave-broadcast
        u32 u = *(const u32*)(xbf + (size_t)sn * 128 + t * 2);
        float xlo = __uint_as_float(u << 16);
        float xhi = __uint_as_float(u & 0xffff0000u);
        a0x += w.x * xlo; a0y += w.x * xhi;
        a1x += w.y * xlo; a1y += w.y * xhi;
        a2x += w.z * xlo; a2y += w.z * xhi;
        a3x += w.w * xlo; a3y += w.w * xhi;
        ws0 += w.x; ws1 += w.y; ws2 += w.z; ws3 += w.w;
    }
    float i0 = 1.f / ws0, i1 = 1.f / ws1, i2 = 1.f / ws2, i3 = 1.f / ws3;
    u16* o = xagg + (size_t)n * 512 + t * 2;
    *(u32*)(o + 0)   = (u32)f2bf(a0x * i0) | ((u32)f2bf(a0y * i0) << 16);
    *(u32*)(o + 128) = (u32)f2bf(a1x * i1) | ((u32)f2bf(a1y * i1) << 16);
    *(u32*)(o + 256) = (u32)f2bf(a2x * i2) | ((u32)f2bf(a2y * i2) << 16);
    *(u32*)(o + 384) = (u32)f2bf(a3x * i3) | ((u32)f2bf(a3y * i3) << 16);
}

// ---- layer-1 GEMM: out1 = elu(xagg_head @ W1_panel + b1), bf16 MFMA -------
// block = 4 waves x 16 rows; grid = (ceil(M/64), 4 heads). No LDS.
__global__ __launch_bounds__(256) void gemm1_mfma(const u16* __restrict__ xagg,
                                                  const u16* __restrict__ W1t,
                                                  const float* __restrict__ b1,
                                                  u16* __restrict__ out1, int M) {
    int wv = threadIdx.x >> 6, l = threadIdx.x & 63;
    int head = blockIdx.y;
    int r0 = blockIdx.x * 64 + wv * 16;
    int lrow = l & 15, kg = l >> 4;

    const u16* arow = xagg + (size_t)(r0 + lrow) * 512 + head * 128 + kg * 4;
    bf16x8 a[4];
#pragma unroll
    for (int s = 0; s < 4; ++s) a[s] = ldfrag(arow + s * 32);

#pragma unroll
    for (int ct = 0; ct < 8; ++ct) {
        int col = head * 128 + ct * 16 + lrow;
        const u16* bcol = W1t + (size_t)(col) * 128 + kg * 4;
        f32x4 acc = {0.f, 0.f, 0.f, 0.f};
#pragma unroll
        for (int s = 0; s < 4; ++s)
            acc = __builtin_amdgcn_mfma_f32_16x16x32_bf16(a[s], ldfrag(bcol + s * 32),
                                                          acc, 0, 0, 0);
        float bias = b1[col];
#pragma unroll
        for (int r = 0; r < 4; ++r) {
            int row = r0 + kg * 4 + r;
            if (row < M) {
                float v = acc[r] + bias;
                out1[(size_t)row * 512 + col] = f2bf(ELU(v));
            }
        }
    }
}

// ---- layer-2 GEMM: h2pre = out1 @ W2, bf16 MFMA, fp32 out -----------------
// block = 4 waves: wave w -> rows blk*32+(w&1)*16, cols (w>>1)*32 (2 tiles).
__global__ __launch_bounds__(256) void gemm2_mfma(const u16* __restrict__ out1,
                                                  const u16* __restrict__ W2t,
                                                  float* __restrict__ h2pre, int M) {
    int wv = threadIdx.x >> 6, l = threadIdx.x & 63;
    int r0 = blockIdx.x * 32 + (wv & 1) * 16;
    int cbase = (wv >> 1) * 32;
    int lrow = l & 15, kg = l >> 4;

    const u16* arow  = out1 + (size_t)(r0 + lrow) * 512 + kg * 4;
    const u16* bcol0 = W2t + (size_t)(cbase + lrow) * 512 + kg * 4;
    const u16* bcol1 = W2t + (size_t)(cbase + 16 + lrow) * 512 + kg * 4;
    f32x4 acc0 = {0.f, 0.f, 0.f, 0.f}, acc1 = acc0;
#pragma unroll
    for (int s = 0; s < 16; ++s) {
        bf16x8 a = ldfrag(arow + s * 32);
        acc0 = __builtin_amdgcn_mfma_f32_16x16x32_bf16(a, ldfrag(bcol0 + s * 32), acc0, 0, 0, 0);
        acc1 = __builtin_amdgcn_mfma_f32_16x16x32_bf16(a, ldfrag(bcol1 + s * 32), acc1, 0, 0, 0);
    }
#pragma unroll
    for (int r = 0; r < 4; ++r) {
        int row = r0 + kg * 4 + r;
        if (row < M) {
            h2pre[(size_t)row * 64 + cbase + lrow]      = acc0[r];
            h2pre[(size_t)row * 64 + cbase + 16 + lrow] = acc1[r];
        }
    }
}

// ---------------- layer-2 logits (H=1, O=64) -------------------------------
__global__ __launch_bounds__(256) void al2_kernel(const float* __restrict__ h2pre,
                                                  const float* __restrict__ a_s,
                                                  const float* __restrict__ a_d,
                                                  float* __restrict__ alS,
                                                  float* __restrict__ alD, int Nn) {
    int n = blockIdx.x * 4 + (threadIdx.x >> 6);
    int lane = threadIdx.x & 63;
    if (n >= Nn) return;
    float v = h2pre[(size_t)n * 64 + lane];
    float s = v * a_s[lane];
    float d = v * a_d[lane];
#pragma unroll
    for (int off = 32; off; off >>= 1) {
        s += __shfl_down(s, off);
        d += __shfl_down(d, off);
    }
    if (lane == 0) { alS[n] = s; alD[n] = d; }
}

__global__ __launch_bounds__(256) void edgew2_kernel(const int* __restrict__ src,
                                                     const int* __restrict__ dst,
                                                     int E, int Nn,
                                                     const float* __restrict__ alS,
                                                     const float* __restrict__ alD,
                                                     float* __restrict__ wE) {
    int e = blockIdx.x * 256 + threadIdx.x;
    if (e >= E + Nn) return;
    int s = (e < E) ? src[e] : (e - E);
    int d = (e < E) ? dst[e] : (e - E);
    float t = alS[s] + alD[d];
    wE[e] = expf(LRELU(t));
}

// ---- layer-2 aggregate + bias + ELU ---------------------------------------
__global__ __launch_bounds__(256) void agg2_kernel(const float* __restrict__ h2pre,
                                                   const int* __restrict__ src,
                                                   const int* __restrict__ offs,
                                                   const int* __restrict__ perm,
                                                   const float* __restrict__ wE,
                                                   const float* __restrict__ b2,
                                                   float* __restrict__ out2,
                                                   int E, int Nn) {
    int n = blockIdx.x * 4 + (threadIdx.x >> 6);
    int f = threadIdx.x & 63;
    if (n >= Nn) return;
    float acc = 0.f, wsum = 0.f;
    int s0 = offs[n], s1 = offs[n + 1];
    for (int i = s0; i < s1; ++i) {
        int eid = perm[i];
        int sn = (eid < E) ? src[eid] : (eid - E);
        float w = wE[eid];
        wsum += w;
        acc += w * h2pre[(size_t)sn * 64 + f];
    }
    float v = acc / wsum + b2[f];
    out2[(size_t)n * 64 + f] = ELU(v);
}

// ---------------- pool + head ----------------------------------------------
__device__ __forceinline__ int lower_bound_i(const int* arr, int n, int key) {
    int lo = 0, hi = n;
    while (lo < hi) {
        int mid = (lo + hi) >> 1;
        if (arr[mid] < key) lo = mid + 1; else hi = mid;
    }
    return lo;
}

__global__ __launch_bounds__(64) void pool_kernel(const float* __restrict__ h2,
                                                  const int* __restrict__ batch,
                                                  int Nn, float* __restrict__ pooled) {
    int g = blockIdx.x;
    __shared__ int sh[2];
    if (threadIdx.x == 0) sh[0] = lower_bound_i(batch, Nn, g);
    if (threadIdx.x == 1) sh[1] = lower_bound_i(batch, Nn, g + 1);
    __syncthreads();
    int s0 = sh[0], s1 = sh[1];
    float sum = 0.f;
    for (int i = s0; i < s1; ++i) sum += h2[(size_t)i * 64 + threadIdx.x];
    float cnt = (float)((s1 - s0) > 1 ? (s1 - s0) : 1);
    pooled[(size_t)g * 64 + threadIdx.x] = sum / cnt;
}

__global__ __launch_bounds__(64) void fc_kernel(const float* __restrict__ pooled,
                                                const float* __restrict__ w1,
                                                const float* __restrict__ bb1,
                                                const float* __restrict__ w2,
                                                const float* __restrict__ bb2,
                                                float* __restrict__ out) {
    int g = blockIdx.x;
    __shared__ float p[64];
    __shared__ float hid[32];
    int t = threadIdx.x;
    p[t] = pooled[(size_t)g * 64 + t];
    __syncthreads();
    if (t < 32) {
        float a = bb1[t];
#pragma unroll
        for (int k = 0; k < 64; ++k) a += p[k] * w1[k * 32 + t];
        hid[t] = a > 0.f ? a : 0.f;
    }
    __syncthreads();
    if (t == 0) {
        float a = bb2[0];
#pragma unroll
        for (int j = 0; j < 32; ++j) a += hid[j] * w2[j];
        out[g] = 1.0f / (1.0f + expf(-a));
    }
}

// ---------------------------------------------------------------------------
extern "C" void kernel_launch(void* const* d_in, const int* in_sizes, int n_in,
                              void* d_out, int out_size, void* d_ws, size_t ws_size,
                              hipStream_t stream) {
    const float* x      = (const float*)d_in[0];
    const int*   ei     = (const int*)d_in[1];
    const int*   batch  = (const int*)d_in[2];
    const float* W1     = (const float*)d_in[3];
    const float* a_src1 = (const float*)d_in[4];
    const float* a_dst1 = (const float*)d_in[5];
    const float* b1     = (const float*)d_in[6];
    const float* W2     = (const float*)d_in[7];
    const float* a_src2 = (const float*)d_in[8];
    const float* a_dst2 = (const float*)d_in[9];
    const float* b2     = (const float*)d_in[10];
    const float* fcw1   = (const float*)d_in[11];
    const float* fcb1   = (const float*)d_in[12];
    const float* fcw2   = (const float*)d_in[13];
    const float* fcb2   = (const float*)d_in[14];
    float* out = (float*)d_out;

    const int Nn = in_sizes[0] / 128;   // 25000
    const int E  = in_sizes[1] / 2;     // 400000
    const int Et = E + Nn;
    const int NG = out_size;            // 512
    const int* srcA = ei;
    const int* dstA = ei + E;

    char* base = (char*)d_ws;
    size_t off = 0;
    auto alloc = [&](size_t bytes) -> void* {
        void* p = base + off;
        off += (bytes + 255) & ~(size_t)255;
        return p;
    };
    u16*   xbf    = (u16*)alloc((size_t)Nn * 128 * 2);
    u16*   xagg   = (u16*)alloc((size_t)Nn * 512 * 2);
    u16*   out1   = (u16*)alloc((size_t)Nn * 512 * 2);
    float* h2pre  = (float*)alloc((size_t)Nn * 64 * 4);
    float* out2   = (float*)alloc((size_t)Nn * 64 * 4);
    u16*   W1t    = (u16*)alloc(512 * 128 * 2);
    u16*   W2t    = (u16*)alloc(64 * 512 * 2);
    float* Wa     = (float*)alloc(128 * 8 * 4);
    float* alS1   = (float*)alloc((size_t)Nn * 4 * 4);
    float* alD1   = (float*)alloc((size_t)Nn * 4 * 4);
    float* alS2   = (float*)alloc((size_t)Nn * 4);
    float* alD2   = (float*)alloc((size_t)Nn * 4);
    float* wE1    = (float*)alloc((size_t)Et * 4 * 4);
    float* wE2    = (float*)alloc((size_t)Et * 4);
    int*   deg    = (int*)alloc((size_t)2 * Nn * 4);
    int*   fill   = deg + Nn;
    int*   offs   = (int*)alloc((size_t)(Nn + 1) * 4);
    int*   bsum   = (int*)alloc(64 * 4);
    int*   perm   = (int*)alloc((size_t)Et * 4);
    float* pooled = (float*)alloc((size_t)NG * 64 * 4);
    (void)ws_size; (void)n_in;

    const int EB = (Et + 255) / 256;
    const int NB = (Nn + 2047) / 2048;

    // ---- casts + layer-1 logits ----
    castx_kernel<<<(Nn * 128 / 4 + 255) / 256, 256, 0, stream>>>(x, xbf, Nn * 128 / 4);
    castw_kernel<<<(512 * 128 + 64 * 512 + 255) / 256, 256, 0, stream>>>(W1, W2, W1t, W2t);
    wa_kernel<<<4, 256, 0, stream>>>(W1, a_src1, a_dst1, Wa);
    al12_kernel<<<(Nn + 3) / 4, 256, 0, stream>>>(x, Wa, alS1, alD1, Nn);

    // ---- CSR build ----
    hipMemsetAsync(deg, 0, sizeof(int) * 2 * Nn, stream);
    count_kernel<<<EB, 256, 0, stream>>>(dstA, E, Nn, deg);
    scanA_kernel<<<NB, 256, 0, stream>>>(deg, offs, bsum, Nn);
    scanB_kernel<<<1, 64, 0, stream>>>(bsum, NB);
    scanC_kernel<<<(Nn + 255) / 256, 256, 0, stream>>>(offs, bsum, Nn);
    scatter_kernel<<<EB, 256, 0, stream>>>(dstA, E, Nn, offs, fill, perm);

    // ---- layer 1 ----
    edgew1_kernel<<<EB, 256, 0, stream>>>(srcA, dstA, E, Nn, alS1, alD1, wE1);
    aggx_kernel<<<Nn, 64, 0, stream>>>(xbf, srcA, offs, perm, wE1, xagg, E);
    dim3 g1((Nn + 63) / 64, 4);
    gemm1_mfma<<<g1, 256, 0, stream>>>(xagg, W1t, b1, out1, Nn);

    // ---- layer 2 ----
    gemm2_mfma<<<(Nn + 31) / 32, 256, 0, stream>>>(out1, W2t, h2pre, Nn);
    al2_kernel<<<(Nn + 3) / 4, 256, 0, stream>>>(h2pre, a_src2, a_dst2, alS2, alD2, Nn);
    edgew2_kernel<<<EB, 256, 0, stream>>>(srcA, dstA, E, Nn, alS2, alD2, wE2);
    agg2_kernel<<<(Nn + 3) / 4, 256, 0, stream>>>(h2pre, srcA, offs, perm, wE2,
                                                  b2, out2, E, Nn);

    // ---- pool + head ----
    pool_kernel<<<NG, 64, 0, stream>>>(out2, batch, Nn, pooled);
    fc_kernel<<<NG, 64, 0, stream>>>(pooled, fcw1, fcb1, fcw2, fcb2, out);
}

// Round 5
// 307.414 us; speedup vs baseline: 1.1607x; 1.1607x over previous
//
#include <hip/hip_runtime.h>
#include <hip/hip_bf16.h>

// ---------------------------------------------------------------------------
// GAT (2 layers) + mean pool + MLP head.
// R3->R4: (a) layer-2 features stored bf16 (halves agg2 gather traffic, the
// top kernel at 68us/64MB fetch); (b) CSR stores src/dst directly (sCSR/dCSR)
// -- no perm indirection, sequential weight reads; (c) castx+al12 fused into
// prep_x (x read once). MFMA GEMMs unchanged from R3.
// ---------------------------------------------------------------------------

typedef unsigned short u16;
typedef unsigned int u32;
typedef __attribute__((ext_vector_type(8))) short bf16x8;
typedef __attribute__((ext_vector_type(4))) float f32x4;

#define LRELU(v) ((v) > 0.0f ? (v) : 0.2f * (v))
#define ELU(v)   ((v) > 0.0f ? (v) : expm1f(v))

__device__ __forceinline__ u16 f2bf(float f) {
    union { float f; u32 u; } c; c.f = f;
    u32 u = c.u;
    u32 r = (u + 0x7fffu + ((u >> 16) & 1u)) >> 16;
    return (u16)r;
}
__device__ __forceinline__ float bf2f(u16 h) {
    return __uint_as_float(((u32)h) << 16);
}

__device__ __forceinline__ bf16x8 ldfrag(const u16* p) {
    ushort4 c0 = *(const ushort4*)(p);
    ushort4 c1 = *(const ushort4*)(p + 16);
    bf16x8 f;
    f[0] = (short)c0.x; f[1] = (short)c0.y; f[2] = (short)c0.z; f[3] = (short)c0.w;
    f[4] = (short)c1.x; f[5] = (short)c1.y; f[6] = (short)c1.z; f[7] = (short)c1.w;
    return f;
}

// ---- W transposes to bf16 [col][k] ----------------------------------------
__global__ __launch_bounds__(256) void castw_kernel(const float* __restrict__ W1,
                                                    const float* __restrict__ W2,
                                                    u16* __restrict__ W1t,
                                                    u16* __restrict__ W2t) {
    int idx = blockIdx.x * 256 + threadIdx.x;
    if (idx < 512 * 128) {
        int c = idx >> 7, k = idx & 127;
        W1t[idx] = f2bf(W1[(size_t)k * 512 + c]);
    }
    int j = idx - 512 * 128;
    if (j >= 0 && j < 64 * 512) {
        int c = j >> 9, k = j & 511;
        W2t[j] = f2bf(W2[(size_t)k * 64 + c]);
    }
}

// ---- fold W1 with a_src/a_dst: Wa[k][j]; j<4 src head j, j>=4 dst ---------
__global__ __launch_bounds__(256) void wa_kernel(const float* __restrict__ W1,
                                                 const float* __restrict__ a_s,
                                                 const float* __restrict__ a_d,
                                                 float* __restrict__ Wa) {
    int idx = blockIdx.x * 256 + threadIdx.x;   // 0..1023
    int k = idx >> 3, j = idx & 7, h = j & 3;
    const float* a = (j < 4) ? (a_s + h * 128) : (a_d + h * 128);
    const float* wrow = W1 + (size_t)k * 512 + h * 128;
    float s = 0.f;
#pragma unroll 8
    for (int o = 0; o < 128; ++o) s += wrow[o] * a[o];
    Wa[k * 8 + j] = s;
}

// ---- prep_x: xbf = bf16(x)  AND  alS1/alD1 = x @ Wa  (fused, one x pass) --
__global__ __launch_bounds__(256) void prep_x(const float* __restrict__ x,
                                              const float* __restrict__ Wa,
                                              u16* __restrict__ xbf,
                                              float* __restrict__ alS,
                                              float* __restrict__ alD, int Nn) {
    int lane = threadIdx.x & 63;
    int wave = threadIdx.x >> 6;
    float4 ls = *(const float4*)(Wa + lane * 8);
    float4 ld = *(const float4*)(Wa + lane * 8 + 4);
    float4 hs = *(const float4*)(Wa + (lane + 64) * 8);
    float4 hd = *(const float4*)(Wa + (lane + 64) * 8 + 4);
    int n = blockIdx.x * 4 + wave;
    if (n >= Nn) return;
    float x0 = x[(size_t)n * 128 + lane];
    float x1 = x[(size_t)n * 128 + lane + 64];
    xbf[(size_t)n * 128 + lane]      = f2bf(x0);
    xbf[(size_t)n * 128 + lane + 64] = f2bf(x1);
    float r0 = x0 * ls.x + x1 * hs.x;
    float r1 = x0 * ls.y + x1 * hs.y;
    float r2 = x0 * ls.z + x1 * hs.z;
    float r3 = x0 * ls.w + x1 * hs.w;
    float r4 = x0 * ld.x + x1 * hd.x;
    float r5 = x0 * ld.y + x1 * hd.y;
    float r6 = x0 * ld.z + x1 * hd.z;
    float r7 = x0 * ld.w + x1 * hd.w;
#pragma unroll
    for (int off = 32; off; off >>= 1) {
        r0 += __shfl_down(r0, off); r1 += __shfl_down(r1, off);
        r2 += __shfl_down(r2, off); r3 += __shfl_down(r3, off);
        r4 += __shfl_down(r4, off); r5 += __shfl_down(r5, off);
        r6 += __shfl_down(r6, off); r7 += __shfl_down(r7, off);
    }
    if (lane == 0) {
        *(float4*)(alS + (size_t)n * 4) = make_float4(r0, r1, r2, r3);
        *(float4*)(alD + (size_t)n * 4) = make_float4(r4, r5, r6, r7);
    }
}

// ---------------- CSR build ------------------------------------------------
__global__ __launch_bounds__(256) void count_kernel(const int* __restrict__ dst,
                                                    int E, int Nn, int* __restrict__ deg) {
    int e = blockIdx.x * 256 + threadIdx.x;
    if (e >= E + Nn) return;
    int d = (e < E) ? dst[e] : (e - E);
    atomicAdd(&deg[d], 1);
}

__global__ __launch_bounds__(256) void scanA_kernel(const int* __restrict__ deg,
                                                    int* __restrict__ offs,
                                                    int* __restrict__ bsum, int n) {
    __shared__ int sh[256];
    int b = blockIdx.x, t = threadIdx.x;
    int base = b * 2048 + t * 8;
    int v[8]; int s = 0;
#pragma unroll
    for (int j = 0; j < 8; ++j) { int i = base + j; v[j] = (i < n) ? deg[i] : 0; s += v[j]; }
    sh[t] = s;
    __syncthreads();
    for (int off = 1; off < 256; off <<= 1) {
        int u = (t >= off) ? sh[t - off] : 0;
        __syncthreads();
        sh[t] += u;
        __syncthreads();
    }
    int run = sh[t] - s;
    if (t == 255) bsum[b] = sh[255];
#pragma unroll
    for (int j = 0; j < 8; ++j) {
        run += v[j];
        int i = base + j;
        if (i < n) offs[i + 1] = run;
    }
}

__global__ __launch_bounds__(64) void scanB_kernel(int* __restrict__ bsum, int nb) {
    int t = threadIdx.x;
    int v = (t < nb) ? bsum[t] : 0;
#pragma unroll
    for (int off = 1; off < 64; off <<= 1) {
        int u = __shfl_up(v, off);
        if (t >= off) v += u;
    }
    if (t < nb) bsum[t] = v;
}

__global__ __launch_bounds__(256) void scanC_kernel(int* __restrict__ offs,
                                                    const int* __restrict__ bsum, int n) {
    int i = blockIdx.x * 256 + threadIdx.x;
    if (i == 0) offs[0] = 0;
    if (i >= n) return;
    int b = i >> 11;
    if (b > 0) offs[i + 1] += bsum[b - 1];
}

// scatter edges into CSR order, storing src/dst directly (no perm)
__global__ __launch_bounds__(256) void scatter_kernel(const int* __restrict__ src,
                                                      const int* __restrict__ dst,
                                                      int E, int Nn,
                                                      const int* __restrict__ offs,
                                                      int* __restrict__ fill,
                                                      int* __restrict__ sCSR,
                                                      int* __restrict__ dCSR) {
    int e = blockIdx.x * 256 + threadIdx.x;
    if (e >= E + Nn) return;
    int s = (e < E) ? src[e] : (e - E);
    int d = (e < E) ? dst[e] : (e - E);
    int pos = offs[d] + atomicAdd(&fill[d], 1);
    sCSR[pos] = s;
    dCSR[pos] = d;
}

// ---- per-position exp weights (CSR order), layer 1 (H=4) ------------------
__global__ __launch_bounds__(256) void edgew1_kernel(const int* __restrict__ sCSR,
                                                     const int* __restrict__ dCSR,
                                                     int Et,
                                                     const float* __restrict__ alS,
                                                     const float* __restrict__ alD,
                                                     float* __restrict__ wE) {
    int i = blockIdx.x * 256 + threadIdx.x;
    if (i >= Et) return;
    int s = sCSR[i], d = dCSR[i];
    float4 as = *(const float4*)(alS + (size_t)s * 4);
    float4 ad = *(const float4*)(alD + (size_t)d * 4);
    float4 w;
    float t;
    t = as.x + ad.x; w.x = expf(LRELU(t));
    t = as.y + ad.y; w.y = expf(LRELU(t));
    t = as.z + ad.z; w.z = expf(LRELU(t));
    t = as.w + ad.w; w.w = expf(LRELU(t));
    *(float4*)(wE + (size_t)i * 4) = w;
}

// ---- layer-1 aggregate of bf16 x -> bf16 xagg (sequential CSR streams) ----
__global__ __launch_bounds__(64) void aggx_kernel(const u16* __restrict__ xbf,
                                                  const int* __restrict__ sCSR,
                                                  const int* __restrict__ offs,
                                                  const float* __restrict__ wE,
                                                  u16* __restrict__ xagg) {
    int n = blockIdx.x;
    int t = threadIdx.x;               // 2 feats per lane
    float a0x = 0.f, a0y = 0.f, a1x = 0.f, a1y = 0.f;
    float a2x = 0.f, a2y = 0.f, a3x = 0.f, a3y = 0.f;
    float ws0 = 0.f, ws1 = 0.f, ws2 = 0.f, ws3 = 0.f;
    int s0 = offs[n], s1 = offs[n + 1];
    for (int i = s0; i < s1; ++i) {
        int sn = sCSR[i];                                    // broadcast
        float4 w = *(const float4*)(wE + (size_t)i * 4);     // sequential
        u32 u = *(const u32*)(xbf + (size_t)sn * 128 + t * 2);
        float xlo = __uint_as_float(u << 16);
        float xhi = __uint_as_float(u & 0xffff0000u);
        a0x += w.x * xlo; a0y += w.x * xhi;
        a1x += w.y * xlo; a1y += w.y * xhi;
        a2x += w.z * xlo; a2y += w.z * xhi;
        a3x += w.w * xlo; a3y += w.w * xhi;
        ws0 += w.x; ws1 += w.y; ws2 += w.z; ws3 += w.w;
    }
    float i0 = 1.f / ws0, i1 = 1.f / ws1, i2 = 1.f / ws2, i3 = 1.f / ws3;
    u16* o = xagg + (size_t)n * 512 + t * 2;
    *(u32*)(o + 0)   = (u32)f2bf(a0x * i0) | ((u32)f2bf(a0y * i0) << 16);
    *(u32*)(o + 128) = (u32)f2bf(a1x * i1) | ((u32)f2bf(a1y * i1) << 16);
    *(u32*)(o + 256) = (u32)f2bf(a2x * i2) | ((u32)f2bf(a2y * i2) << 16);
    *(u32*)(o + 384) = (u32)f2bf(a3x * i3) | ((u32)f2bf(a3y * i3) << 16);
}

// ---- layer-1 GEMM: out1 = elu(xagg_head @ W1_panel + b1), bf16 MFMA -------
__global__ __launch_bounds__(256) void gemm1_mfma(const u16* __restrict__ xagg,
                                                  const u16* __restrict__ W1t,
                                                  const float* __restrict__ b1,
                                                  u16* __restrict__ out1, int M) {
    int wv = threadIdx.x >> 6, l = threadIdx.x & 63;
    int head = blockIdx.y;
    int r0 = blockIdx.x * 64 + wv * 16;
    int lrow = l & 15, kg = l >> 4;

    const u16* arow = xagg + (size_t)(r0 + lrow) * 512 + head * 128 + kg * 4;
    bf16x8 a[4];
#pragma unroll
    for (int s = 0; s < 4; ++s) a[s] = ldfrag(arow + s * 32);

#pragma unroll
    for (int ct = 0; ct < 8; ++ct) {
        int col = head * 128 + ct * 16 + lrow;
        const u16* bcol = W1t + (size_t)(col) * 128 + kg * 4;
        f32x4 acc = {0.f, 0.f, 0.f, 0.f};
#pragma unroll
        for (int s = 0; s < 4; ++s)
            acc = __builtin_amdgcn_mfma_f32_16x16x32_bf16(a[s], ldfrag(bcol + s * 32),
                                                          acc, 0, 0, 0);
        float bias = b1[col];
#pragma unroll
        for (int r = 0; r < 4; ++r) {
            int row = r0 + kg * 4 + r;
            if (row < M) {
                float v = acc[r] + bias;
                out1[(size_t)row * 512 + col] = f2bf(ELU(v));
            }
        }
    }
}

// ---- layer-2 GEMM: h2bf = bf16(out1 @ W2), bf16 MFMA ----------------------
__global__ __launch_bounds__(256) void gemm2_mfma(const u16* __restrict__ out1,
                                                  const u16* __restrict__ W2t,
                                                  u16* __restrict__ h2bf, int M) {
    int wv = threadIdx.x >> 6, l = threadIdx.x & 63;
    int r0 = blockIdx.x * 32 + (wv & 1) * 16;
    int cbase = (wv >> 1) * 32;
    int lrow = l & 15, kg = l >> 4;

    const u16* arow  = out1 + (size_t)(r0 + lrow) * 512 + kg * 4;
    const u16* bcol0 = W2t + (size_t)(cbase + lrow) * 512 + kg * 4;
    const u16* bcol1 = W2t + (size_t)(cbase + 16 + lrow) * 512 + kg * 4;
    f32x4 acc0 = {0.f, 0.f, 0.f, 0.f}, acc1 = acc0;
#pragma unroll
    for (int s = 0; s < 16; ++s) {
        bf16x8 a = ldfrag(arow + s * 32);
        acc0 = __builtin_amdgcn_mfma_f32_16x16x32_bf16(a, ldfrag(bcol0 + s * 32), acc0, 0, 0, 0);
        acc1 = __builtin_amdgcn_mfma_f32_16x16x32_bf16(a, ldfrag(bcol1 + s * 32), acc1, 0, 0, 0);
    }
#pragma unroll
    for (int r = 0; r < 4; ++r) {
        int row = r0 + kg * 4 + r;
        if (row < M) {
            h2bf[(size_t)row * 64 + cbase + lrow]      = f2bf(acc0[r]);
            h2bf[(size_t)row * 64 + cbase + 16 + lrow] = f2bf(acc1[r]);
        }
    }
}

// ---------------- layer-2 logits (H=1, O=64), bf16 input -------------------
__global__ __launch_bounds__(256) void al2_kernel(const u16* __restrict__ h2bf,
                                                  const float* __restrict__ a_s,
                                                  const float* __restrict__ a_d,
                                                  float* __restrict__ alS,
                                                  float* __restrict__ alD, int Nn) {
    int n = blockIdx.x * 4 + (threadIdx.x >> 6);
    int lane = threadIdx.x & 63;
    if (n >= Nn) return;
    float v = bf2f(h2bf[(size_t)n * 64 + lane]);
    float s = v * a_s[lane];
    float d = v * a_d[lane];
#pragma unroll
    for (int off = 32; off; off >>= 1) {
        s += __shfl_down(s, off);
        d += __shfl_down(d, off);
    }
    if (lane == 0) { alS[n] = s; alD[n] = d; }
}

__global__ __launch_bounds__(256) void edgew2_kernel(const int* __restrict__ sCSR,
                                                     const int* __restrict__ dCSR,
                                                     int Et,
                                                     const float* __restrict__ alS,
                                                     const float* __restrict__ alD,
                                                     float* __restrict__ wE) {
    int i = blockIdx.x * 256 + threadIdx.x;
    if (i >= Et) return;
    int s = sCSR[i], d = dCSR[i];
    float t = alS[s] + alD[d];
    wE[i] = expf(LRELU(t));
}

// ---- layer-2 aggregate (bf16 gather) + bias + ELU -------------------------
__global__ __launch_bounds__(256) void agg2_kernel(const u16* __restrict__ h2bf,
                                                   const int* __restrict__ sCSR,
                                                   const int* __restrict__ offs,
                                                   const float* __restrict__ wE,
                                                   const float* __restrict__ b2,
                                                   float* __restrict__ out2, int Nn) {
    int n = blockIdx.x * 4 + (threadIdx.x >> 6);
    int f = threadIdx.x & 63;
    if (n >= Nn) return;
    float acc = 0.f, wsum = 0.f;
    int s0 = offs[n], s1 = offs[n + 1];
    for (int i = s0; i < s1; ++i) {
        int sn = sCSR[i];
        float w = wE[i];
        wsum += w;
        acc += w * bf2f(h2bf[(size_t)sn * 64 + f]);
    }
    float v = acc / wsum + b2[f];
    out2[(size_t)n * 64 + f] = ELU(v);
}

// ---------------- pool + head ----------------------------------------------
__device__ __forceinline__ int lower_bound_i(const int* arr, int n, int key) {
    int lo = 0, hi = n;
    while (lo < hi) {
        int mid = (lo + hi) >> 1;
        if (arr[mid] < key) lo = mid + 1; else hi = mid;
    }
    return lo;
}

__global__ __launch_bounds__(64) void pool_kernel(const float* __restrict__ h2,
                                                  const int* __restrict__ batch,
                                                  int Nn, float* __restrict__ pooled) {
    int g = blockIdx.x;
    __shared__ int sh[2];
    if (threadIdx.x == 0) sh[0] = lower_bound_i(batch, Nn, g);
    if (threadIdx.x == 1) sh[1] = lower_bound_i(batch, Nn, g + 1);
    __syncthreads();
    int s0 = sh[0], s1 = sh[1];
    float sum = 0.f;
    for (int i = s0; i < s1; ++i) sum += h2[(size_t)i * 64 + threadIdx.x];
    float cnt = (float)((s1 - s0) > 1 ? (s1 - s0) : 1);
    pooled[(size_t)g * 64 + threadIdx.x] = sum / cnt;
}

__global__ __launch_bounds__(64) void fc_kernel(const float* __restrict__ pooled,
                                                const float* __restrict__ w1,
                                                const float* __restrict__ bb1,
                                                const float* __restrict__ w2,
                                                const float* __restrict__ bb2,
                                                float* __restrict__ out) {
    int g = blockIdx.x;
    __shared__ float p[64];
    __shared__ float hid[32];
    int t = threadIdx.x;
    p[t] = pooled[(size_t)g * 64 + t];
    __syncthreads();
    if (t < 32) {
        float a = bb1[t];
#pragma unroll
        for (int k = 0; k < 64; ++k) a += p[k] * w1[k * 32 + t];
        hid[t] = a > 0.f ? a : 0.f;
    }
    __syncthreads();
    if (t == 0) {
        float a = bb2[0];
#pragma unroll
        for (int j = 0; j < 32; ++j) a += hid[j] * w2[j];
        out[g] = 1.0f / (1.0f + expf(-a));
    }
}

// ---------------------------------------------------------------------------
extern "C" void kernel_launch(void* const* d_in, const int* in_sizes, int n_in,
                              void* d_out, int out_size, void* d_ws, size_t ws_size,
                              hipStream_t stream) {
    const float* x      = (const float*)d_in[0];
    const int*   ei     = (const int*)d_in[1];
    const int*   batch  = (const int*)d_in[2];
    const float* W1     = (const float*)d_in[3];
    const float* a_src1 = (const float*)d_in[4];
    const float* a_dst1 = (const float*)d_in[5];
    const float* b1     = (const float*)d_in[6];
    const float* W2     = (const float*)d_in[7];
    const float* a_src2 = (const float*)d_in[8];
    const float* a_dst2 = (const float*)d_in[9];
    const float* b2     = (const float*)d_in[10];
    const float* fcw1   = (const float*)d_in[11];
    const float* fcb1   = (const float*)d_in[12];
    const float* fcw2   = (const float*)d_in[13];
    const float* fcb2   = (const float*)d_in[14];
    float* out = (float*)d_out;

    const int Nn = in_sizes[0] / 128;   // 25000
    const int E  = in_sizes[1] / 2;     // 400000
    const int Et = E + Nn;
    const int NG = out_size;            // 512
    const int* srcA = ei;
    const int* dstA = ei + E;

    char* base = (char*)d_ws;
    size_t off = 0;
    auto alloc = [&](size_t bytes) -> void* {
        void* p = base + off;
        off += (bytes + 255) & ~(size_t)255;
        return p;
    };
    u16*   xbf    = (u16*)alloc((size_t)Nn * 128 * 2);
    u16*   xagg   = (u16*)alloc((size_t)Nn * 512 * 2);
    u16*   out1   = (u16*)alloc((size_t)Nn * 512 * 2);
    u16*   h2bf   = (u16*)alloc((size_t)Nn * 64 * 2);
    float* out2   = (float*)alloc((size_t)Nn * 64 * 4);
    u16*   W1t    = (u16*)alloc(512 * 128 * 2);
    u16*   W2t    = (u16*)alloc(64 * 512 * 2);
    float* Wa     = (float*)alloc(128 * 8 * 4);
    float* alS1   = (float*)alloc((size_t)Nn * 4 * 4);
    float* alD1   = (float*)alloc((size_t)Nn * 4 * 4);
    float* alS2   = (float*)alloc((size_t)Nn * 4);
    float* alD2   = (float*)alloc((size_t)Nn * 4);
    float* wE1    = (float*)alloc((size_t)Et * 4 * 4);
    float* wE2    = (float*)alloc((size_t)Et * 4);
    int*   deg    = (int*)alloc((size_t)2 * Nn * 4);
    int*   fill   = deg + Nn;
    int*   offs   = (int*)alloc((size_t)(Nn + 1) * 4);
    int*   bsum   = (int*)alloc(64 * 4);
    int*   sCSR   = (int*)alloc((size_t)Et * 4);
    int*   dCSR   = (int*)alloc((size_t)Et * 4);
    float* pooled = (float*)alloc((size_t)NG * 64 * 4);
    (void)ws_size; (void)n_in;

    const int EB = (Et + 255) / 256;
    const int NB = (Nn + 2047) / 2048;

    // ---- weight prep + fused x prep ----
    castw_kernel<<<(512 * 128 + 64 * 512 + 255) / 256, 256, 0, stream>>>(W1, W2, W1t, W2t);
    wa_kernel<<<4, 256, 0, stream>>>(W1, a_src1, a_dst1, Wa);
    prep_x<<<(Nn + 3) / 4, 256, 0, stream>>>(x, Wa, xbf, alS1, alD1, Nn);

    // ---- CSR build ----
    hipMemsetAsync(deg, 0, sizeof(int) * 2 * Nn, stream);
    count_kernel<<<EB, 256, 0, stream>>>(dstA, E, Nn, deg);
    scanA_kernel<<<NB, 256, 0, stream>>>(deg, offs, bsum, Nn);
    scanB_kernel<<<1, 64, 0, stream>>>(bsum, NB);
    scanC_kernel<<<(Nn + 255) / 256, 256, 0, stream>>>(offs, bsum, Nn);
    scatter_kernel<<<EB, 256, 0, stream>>>(srcA, dstA, E, Nn, offs, fill, sCSR, dCSR);

    // ---- layer 1 ----
    edgew1_kernel<<<EB, 256, 0, stream>>>(sCSR, dCSR, Et, alS1, alD1, wE1);
    aggx_kernel<<<Nn, 64, 0, stream>>>(xbf, sCSR, offs, wE1, xagg);
    dim3 g1((Nn + 63) / 64, 4);
    gemm1_mfma<<<g1, 256, 0, stream>>>(xagg, W1t, b1, out1, Nn);

    // ---- layer 2 ----
    gemm2_mfma<<<(Nn + 31) / 32, 256, 0, stream>>>(out1, W2t, h2bf, Nn);
    al2_kernel<<<(Nn + 3) / 4, 256, 0, stream>>>(h2bf, a_src2, a_dst2, alS2, alD2, Nn);
    edgew2_kernel<<<EB, 256, 0, stream>>>(sCSR, dCSR, Et, alS2, alD2, wE2);
    agg2_kernel<<<(Nn + 3) / 4, 256, 0, stream>>>(h2bf, sCSR, offs, wE2, b2, out2, Nn);

    // ---- pool + head ----
    pool_kernel<<<NG, 64, 0, stream>>>(out2, batch, Nn, pooled);
    fc_kernel<<<NG, 64, 0, stream>>>(pooled, fcw1, fcb1, fcw2, fcb2, out);
}

// Round 6
// 279.446 us; speedup vs baseline: 1.2769x; 1.1001x over previous
//
#include <hip/hip_runtime.h>
#include <hip/hip_bf16.h>

// ---------------------------------------------------------------------------
// GAT (2 layers) + mean pool + MLP head.
// R4->R5: both MFMA GEMMs rewritten with swapped operands (A=W frag, B=x frag
// => D holds 4 consecutive out-cols per lane => 8B packed stores) and explicit
// register tiling (x fragments held across col-blocks). R4's gemm1 compiled to
// 24 VGPR => serialized latency-bound chains (MfmaUtil 1.8%). al2 fused into
// gemm2's epilogue (cross-lane reduce), al2 dispatch deleted.
// ---------------------------------------------------------------------------

typedef unsigned short u16;
typedef unsigned int u32;
typedef __attribute__((ext_vector_type(8))) short bf16x8;
typedef __attribute__((ext_vector_type(4))) float f32x4;

#define LRELU(v) ((v) > 0.0f ? (v) : 0.2f * (v))
#define ELU(v)   ((v) > 0.0f ? (v) : expm1f(v))

__device__ __forceinline__ u16 f2bf(float f) {
    union { float f; u32 u; } c; c.f = f;
    u32 u = c.u;
    u32 r = (u + 0x7fffu + ((u >> 16) & 1u)) >> 16;
    return (u16)r;
}
__device__ __forceinline__ float bf2f(u16 h) {
    return __uint_as_float(((u32)h) << 16);
}

__device__ __forceinline__ bf16x8 ldfrag(const u16* p) {
    ushort4 c0 = *(const ushort4*)(p);
    ushort4 c1 = *(const ushort4*)(p + 16);
    bf16x8 f;
    f[0] = (short)c0.x; f[1] = (short)c0.y; f[2] = (short)c0.z; f[3] = (short)c0.w;
    f[4] = (short)c1.x; f[5] = (short)c1.y; f[6] = (short)c1.z; f[7] = (short)c1.w;
    return f;
}

// ---- W transposes to bf16 [col][k] ----------------------------------------
__global__ __launch_bounds__(256) void castw_kernel(const float* __restrict__ W1,
                                                    const float* __restrict__ W2,
                                                    u16* __restrict__ W1t,
                                                    u16* __restrict__ W2t) {
    int idx = blockIdx.x * 256 + threadIdx.x;
    if (idx < 512 * 128) {
        int c = idx >> 7, k = idx & 127;
        W1t[idx] = f2bf(W1[(size_t)k * 512 + c]);
    }
    int j = idx - 512 * 128;
    if (j >= 0 && j < 64 * 512) {
        int c = j >> 9, k = j & 511;
        W2t[j] = f2bf(W2[(size_t)k * 64 + c]);
    }
}

// ---- fold W1 with a_src/a_dst: Wa[k][j]; j<4 src head j, j>=4 dst ---------
__global__ __launch_bounds__(256) void wa_kernel(const float* __restrict__ W1,
                                                 const float* __restrict__ a_s,
                                                 const float* __restrict__ a_d,
                                                 float* __restrict__ Wa) {
    int idx = blockIdx.x * 256 + threadIdx.x;   // 0..1023
    int k = idx >> 3, j = idx & 7, h = j & 3;
    const float* a = (j < 4) ? (a_s + h * 128) : (a_d + h * 128);
    const float* wrow = W1 + (size_t)k * 512 + h * 128;
    float s = 0.f;
#pragma unroll 8
    for (int o = 0; o < 128; ++o) s += wrow[o] * a[o];
    Wa[k * 8 + j] = s;
}

// ---- prep_x: xbf = bf16(x)  AND  alS1/alD1 = x @ Wa  (fused, one x pass) --
__global__ __launch_bounds__(256) void prep_x(const float* __restrict__ x,
                                              const float* __restrict__ Wa,
                                              u16* __restrict__ xbf,
                                              float* __restrict__ alS,
                                              float* __restrict__ alD, int Nn) {
    int lane = threadIdx.x & 63;
    int wave = threadIdx.x >> 6;
    float4 ls = *(const float4*)(Wa + lane * 8);
    float4 ld = *(const float4*)(Wa + lane * 8 + 4);
    float4 hs = *(const float4*)(Wa + (lane + 64) * 8);
    float4 hd = *(const float4*)(Wa + (lane + 64) * 8 + 4);
    int n = blockIdx.x * 4 + wave;
    if (n >= Nn) return;
    float x0 = x[(size_t)n * 128 + lane];
    float x1 = x[(size_t)n * 128 + lane + 64];
    xbf[(size_t)n * 128 + lane]      = f2bf(x0);
    xbf[(size_t)n * 128 + lane + 64] = f2bf(x1);
    float r0 = x0 * ls.x + x1 * hs.x;
    float r1 = x0 * ls.y + x1 * hs.y;
    float r2 = x0 * ls.z + x1 * hs.z;
    float r3 = x0 * ls.w + x1 * hs.w;
    float r4 = x0 * ld.x + x1 * hd.x;
    float r5 = x0 * ld.y + x1 * hd.y;
    float r6 = x0 * ld.z + x1 * hd.z;
    float r7 = x0 * ld.w + x1 * hd.w;
#pragma unroll
    for (int off = 32; off; off >>= 1) {
        r0 += __shfl_down(r0, off); r1 += __shfl_down(r1, off);
        r2 += __shfl_down(r2, off); r3 += __shfl_down(r3, off);
        r4 += __shfl_down(r4, off); r5 += __shfl_down(r5, off);
        r6 += __shfl_down(r6, off); r7 += __shfl_down(r7, off);
    }
    if (lane == 0) {
        *(float4*)(alS + (size_t)n * 4) = make_float4(r0, r1, r2, r3);
        *(float4*)(alD + (size_t)n * 4) = make_float4(r4, r5, r6, r7);
    }
}

// ---------------- CSR build ------------------------------------------------
__global__ __launch_bounds__(256) void count_kernel(const int* __restrict__ dst,
                                                    int E, int Nn, int* __restrict__ deg) {
    int e = blockIdx.x * 256 + threadIdx.x;
    if (e >= E + Nn) return;
    int d = (e < E) ? dst[e] : (e - E);
    atomicAdd(&deg[d], 1);
}

__global__ __launch_bounds__(256) void scanA_kernel(const int* __restrict__ deg,
                                                    int* __restrict__ offs,
                                                    int* __restrict__ bsum, int n) {
    __shared__ int sh[256];
    int b = blockIdx.x, t = threadIdx.x;
    int base = b * 2048 + t * 8;
    int v[8]; int s = 0;
#pragma unroll
    for (int j = 0; j < 8; ++j) { int i = base + j; v[j] = (i < n) ? deg[i] : 0; s += v[j]; }
    sh[t] = s;
    __syncthreads();
    for (int off = 1; off < 256; off <<= 1) {
        int u = (t >= off) ? sh[t - off] : 0;
        __syncthreads();
        sh[t] += u;
        __syncthreads();
    }
    int run = sh[t] - s;
    if (t == 255) bsum[b] = sh[255];
#pragma unroll
    for (int j = 0; j < 8; ++j) {
        run += v[j];
        int i = base + j;
        if (i < n) offs[i + 1] = run;
    }
}

__global__ __launch_bounds__(64) void scanB_kernel(int* __restrict__ bsum, int nb) {
    int t = threadIdx.x;
    int v = (t < nb) ? bsum[t] : 0;
#pragma unroll
    for (int off = 1; off < 64; off <<= 1) {
        int u = __shfl_up(v, off);
        if (t >= off) v += u;
    }
    if (t < nb) bsum[t] = v;
}

__global__ __launch_bounds__(256) void scanC_kernel(int* __restrict__ offs,
                                                    const int* __restrict__ bsum, int n) {
    int i = blockIdx.x * 256 + threadIdx.x;
    if (i == 0) offs[0] = 0;
    if (i >= n) return;
    int b = i >> 11;
    if (b > 0) offs[i + 1] += bsum[b - 1];
}

// scatter edges into CSR order, storing src/dst directly (no perm)
__global__ __launch_bounds__(256) void scatter_kernel(const int* __restrict__ src,
                                                      const int* __restrict__ dst,
                                                      int E, int Nn,
                                                      const int* __restrict__ offs,
                                                      int* __restrict__ fill,
                                                      int* __restrict__ sCSR,
                                                      int* __restrict__ dCSR) {
    int e = blockIdx.x * 256 + threadIdx.x;
    if (e >= E + Nn) return;
    int s = (e < E) ? src[e] : (e - E);
    int d = (e < E) ? dst[e] : (e - E);
    int pos = offs[d] + atomicAdd(&fill[d], 1);
    sCSR[pos] = s;
    dCSR[pos] = d;
}

// ---- per-position exp weights (CSR order), layer 1 (H=4) ------------------
__global__ __launch_bounds__(256) void edgew1_kernel(const int* __restrict__ sCSR,
                                                     const int* __restrict__ dCSR,
                                                     int Et,
                                                     const float* __restrict__ alS,
                                                     const float* __restrict__ alD,
                                                     float* __restrict__ wE) {
    int i = blockIdx.x * 256 + threadIdx.x;
    if (i >= Et) return;
    int s = sCSR[i], d = dCSR[i];
    float4 as = *(const float4*)(alS + (size_t)s * 4);
    float4 ad = *(const float4*)(alD + (size_t)d * 4);
    float4 w;
    float t;
    t = as.x + ad.x; w.x = expf(LRELU(t));
    t = as.y + ad.y; w.y = expf(LRELU(t));
    t = as.z + ad.z; w.z = expf(LRELU(t));
    t = as.w + ad.w; w.w = expf(LRELU(t));
    *(float4*)(wE + (size_t)i * 4) = w;
}

// ---- layer-1 aggregate of bf16 x -> bf16 xagg (sequential CSR streams) ----
__global__ __launch_bounds__(64) void aggx_kernel(const u16* __restrict__ xbf,
                                                  const int* __restrict__ sCSR,
                                                  const int* __restrict__ offs,
                                                  const float* __restrict__ wE,
                                                  u16* __restrict__ xagg) {
    int n = blockIdx.x;
    int t = threadIdx.x;               // 2 feats per lane
    float a0x = 0.f, a0y = 0.f, a1x = 0.f, a1y = 0.f;
    float a2x = 0.f, a2y = 0.f, a3x = 0.f, a3y = 0.f;
    float ws0 = 0.f, ws1 = 0.f, ws2 = 0.f, ws3 = 0.f;
    int s0 = offs[n], s1 = offs[n + 1];
    for (int i = s0; i < s1; ++i) {
        int sn = sCSR[i];                                    // broadcast
        float4 w = *(const float4*)(wE + (size_t)i * 4);     // sequential
        u32 u = *(const u32*)(xbf + (size_t)sn * 128 + t * 2);
        float xlo = __uint_as_float(u << 16);
        float xhi = __uint_as_float(u & 0xffff0000u);
        a0x += w.x * xlo; a0y += w.x * xhi;
        a1x += w.y * xlo; a1y += w.y * xhi;
        a2x += w.z * xlo; a2y += w.z * xhi;
        a3x += w.w * xlo; a3y += w.w * xhi;
        ws0 += w.x; ws1 += w.y; ws2 += w.z; ws3 += w.w;
    }
    float i0 = 1.f / ws0, i1 = 1.f / ws1, i2 = 1.f / ws2, i3 = 1.f / ws3;
    u16* o = xagg + (size_t)n * 512 + t * 2;
    *(u32*)(o + 0)   = (u32)f2bf(a0x * i0) | ((u32)f2bf(a0y * i0) << 16);
    *(u32*)(o + 128) = (u32)f2bf(a1x * i1) | ((u32)f2bf(a1y * i1) << 16);
    *(u32*)(o + 256) = (u32)f2bf(a2x * i2) | ((u32)f2bf(a2y * i2) << 16);
    *(u32*)(o + 384) = (u32)f2bf(a3x * i3) | ((u32)f2bf(a3y * i3) << 16);
}

// ---- layer-1 GEMM: out1 = elu(xagg_head @ W1_panel + b1), bf16 MFMA -------
// Swapped operands: D = out1^T tile; lane stores 4 consecutive cols (8B).
// Wave = 32 nodes x 128 cols; block = 4 waves (128 nodes); grid.y = head.
__global__ __launch_bounds__(256) void gemm1_mfma(const u16* __restrict__ xagg,
                                                  const u16* __restrict__ W1t,
                                                  const float* __restrict__ b1,
                                                  u16* __restrict__ out1, int M) {
    int wv = threadIdx.x >> 6, l = threadIdx.x & 63;
    int head = blockIdx.y;
    int nb = blockIdx.x * 128 + wv * 32;
    int lrow = l & 15, kg = l >> 4;

    // x fragments for 2 node-groups, held across all col-blocks
    bf16x8 xf[2][4];
#pragma unroll
    for (int g = 0; g < 2; ++g) {
        const u16* xr = xagg + (size_t)(nb + g * 16 + lrow) * 512 + head * 128 + kg * 4;
#pragma unroll
        for (int s = 0; s < 4; ++s) xf[g][s] = ldfrag(xr + s * 32);
    }

#pragma unroll
    for (int cb = 0; cb < 8; ++cb) {
        int c0 = head * 128 + cb * 16;
        const u16* wc = W1t + (size_t)(c0 + lrow) * 128 + kg * 4;
        bf16x8 wf[4];
#pragma unroll
        for (int s = 0; s < 4; ++s) wf[s] = ldfrag(wc + s * 32);
        float4 bias = *(const float4*)(b1 + c0 + kg * 4);
#pragma unroll
        for (int g = 0; g < 2; ++g) {
            f32x4 acc = {0.f, 0.f, 0.f, 0.f};
#pragma unroll
            for (int s = 0; s < 4; ++s)
                acc = __builtin_amdgcn_mfma_f32_16x16x32_bf16(wf[s], xf[g][s], acc, 0, 0, 0);
            int node = nb + g * 16 + lrow;
            if (node < M) {
                float v0 = acc[0] + bias.x, v1 = acc[1] + bias.y;
                float v2 = acc[2] + bias.z, v3 = acc[3] + bias.w;
                ushort4 o;
                o.x = f2bf(ELU(v0)); o.y = f2bf(ELU(v1));
                o.z = f2bf(ELU(v2)); o.w = f2bf(ELU(v3));
                *(ushort4*)(out1 + (size_t)node * 512 + c0 + kg * 4) = o;
            }
        }
    }
}

// ---- layer-2 GEMM + fused al2: h2bf = bf16(out1 @ W2); alS2/alD2 ----------
// Swapped operands; wave = 16 nodes x 64 cols, K=512; block = 4 waves.
__global__ __launch_bounds__(256) void gemm2_mfma(const u16* __restrict__ out1,
                                                  const u16* __restrict__ W2t,
                                                  const float* __restrict__ a_s2,
                                                  const float* __restrict__ a_d2,
                                                  u16* __restrict__ h2bf,
                                                  float* __restrict__ alS,
                                                  float* __restrict__ alD, int M) {
    int wv = threadIdx.x >> 6, l = threadIdx.x & 63;
    int nb = blockIdx.x * 64 + wv * 16;
    int lrow = l & 15, kg = l >> 4;

    const u16* xr = out1 + (size_t)(nb + lrow) * 512 + kg * 4;
    bf16x8 xf[16];
#pragma unroll
    for (int s = 0; s < 16; ++s) xf[s] = ldfrag(xr + s * 32);

    int node = nb + lrow;
    float ps = 0.f, pd = 0.f;
#pragma unroll
    for (int cb = 0; cb < 4; ++cb) {
        int c0 = cb * 16;
        const u16* wc = W2t + (size_t)(c0 + lrow) * 512 + kg * 4;
        f32x4 acc = {0.f, 0.f, 0.f, 0.f};
#pragma unroll
        for (int s = 0; s < 16; ++s)
            acc = __builtin_amdgcn_mfma_f32_16x16x32_bf16(ldfrag(wc + s * 32), xf[s],
                                                          acc, 0, 0, 0);
        float4 as = *(const float4*)(a_s2 + c0 + kg * 4);
        float4 ad = *(const float4*)(a_d2 + c0 + kg * 4);
        ps += acc[0] * as.x + acc[1] * as.y + acc[2] * as.z + acc[3] * as.w;
        pd += acc[0] * ad.x + acc[1] * ad.y + acc[2] * ad.z + acc[3] * ad.w;
        if (node < M) {
            ushort4 o;
            o.x = f2bf(acc[0]); o.y = f2bf(acc[1]);
            o.z = f2bf(acc[2]); o.w = f2bf(acc[3]);
            *(ushort4*)(h2bf + (size_t)node * 64 + c0 + kg * 4) = o;
        }
    }
    // reduce partial dots across kg (lanes l, l^16, l^32, l^48 share lrow)
    ps += __shfl_xor(ps, 16); ps += __shfl_xor(ps, 32);
    pd += __shfl_xor(pd, 16); pd += __shfl_xor(pd, 32);
    if (kg == 0 && node < M) { alS[node] = ps; alD[node] = pd; }
}

__global__ __launch_bounds__(256) void edgew2_kernel(const int* __restrict__ sCSR,
                                                     const int* __restrict__ dCSR,
                                                     int Et,
                                                     const float* __restrict__ alS,
                                                     const float* __restrict__ alD,
                                                     float* __restrict__ wE) {
    int i = blockIdx.x * 256 + threadIdx.x;
    if (i >= Et) return;
    int s = sCSR[i], d = dCSR[i];
    float t = alS[s] + alD[d];
    wE[i] = expf(LRELU(t));
}

// ---- layer-2 aggregate (bf16 gather) + bias + ELU -------------------------
__global__ __launch_bounds__(256) void agg2_kernel(const u16* __restrict__ h2bf,
                                                   const int* __restrict__ sCSR,
                                                   const int* __restrict__ offs,
                                                   const float* __restrict__ wE,
                                                   const float* __restrict__ b2,
                                                   float* __restrict__ out2, int Nn) {
    int n = blockIdx.x * 4 + (threadIdx.x >> 6);
    int f = threadIdx.x & 63;
    if (n >= Nn) return;
    float acc = 0.f, wsum = 0.f;
    int s0 = offs[n], s1 = offs[n + 1];
    for (int i = s0; i < s1; ++i) {
        int sn = sCSR[i];
        float w = wE[i];
        wsum += w;
        acc += w * bf2f(h2bf[(size_t)sn * 64 + f]);
    }
    float v = acc / wsum + b2[f];
    out2[(size_t)n * 64 + f] = ELU(v);
}

// ---------------- pool + head ----------------------------------------------
__device__ __forceinline__ int lower_bound_i(const int* arr, int n, int key) {
    int lo = 0, hi = n;
    while (lo < hi) {
        int mid = (lo + hi) >> 1;
        if (arr[mid] < key) lo = mid + 1; else hi = mid;
    }
    return lo;
}

__global__ __launch_bounds__(64) void pool_kernel(const float* __restrict__ h2,
                                                  const int* __restrict__ batch,
                                                  int Nn, float* __restrict__ pooled) {
    int g = blockIdx.x;
    __shared__ int sh[2];
    if (threadIdx.x == 0) sh[0] = lower_bound_i(batch, Nn, g);
    if (threadIdx.x == 1) sh[1] = lower_bound_i(batch, Nn, g + 1);
    __syncthreads();
    int s0 = sh[0], s1 = sh[1];
    float sum = 0.f;
    for (int i = s0; i < s1; ++i) sum += h2[(size_t)i * 64 + threadIdx.x];
    float cnt = (float)((s1 - s0) > 1 ? (s1 - s0) : 1);
    pooled[(size_t)g * 64 + threadIdx.x] = sum / cnt;
}

__global__ __launch_bounds__(64) void fc_kernel(const float* __restrict__ pooled,
                                                const float* __restrict__ w1,
                                                const float* __restrict__ bb1,
                                                const float* __restrict__ w2,
                                                const float* __restrict__ bb2,
                                                float* __restrict__ out) {
    int g = blockIdx.x;
    __shared__ float p[64];
    __shared__ float hid[32];
    int t = threadIdx.x;
    p[t] = pooled[(size_t)g * 64 + t];
    __syncthreads();
    if (t < 32) {
        float a = bb1[t];
#pragma unroll
        for (int k = 0; k < 64; ++k) a += p[k] * w1[k * 32 + t];
        hid[t] = a > 0.f ? a : 0.f;
    }
    __syncthreads();
    if (t == 0) {
        float a = bb2[0];
#pragma unroll
        for (int j = 0; j < 32; ++j) a += hid[j] * w2[j];
        out[g] = 1.0f / (1.0f + expf(-a));
    }
}

// ---------------------------------------------------------------------------
extern "C" void kernel_launch(void* const* d_in, const int* in_sizes, int n_in,
                              void* d_out, int out_size, void* d_ws, size_t ws_size,
                              hipStream_t stream) {
    const float* x      = (const float*)d_in[0];
    const int*   ei     = (const int*)d_in[1];
    const int*   batch  = (const int*)d_in[2];
    const float* W1     = (const float*)d_in[3];
    const float* a_src1 = (const float*)d_in[4];
    const float* a_dst1 = (const float*)d_in[5];
    const float* b1     = (const float*)d_in[6];
    const float* W2     = (const float*)d_in[7];
    const float* a_src2 = (const float*)d_in[8];
    const float* a_dst2 = (const float*)d_in[9];
    const float* b2     = (const float*)d_in[10];
    const float* fcw1   = (const float*)d_in[11];
    const float* fcb1   = (const float*)d_in[12];
    const float* fcw2   = (const float*)d_in[13];
    const float* fcb2   = (const float*)d_in[14];
    float* out = (float*)d_out;

    const int Nn = in_sizes[0] / 128;   // 25000
    const int E  = in_sizes[1] / 2;     // 400000
    const int Et = E + Nn;
    const int NG = out_size;            // 512
    const int* srcA = ei;
    const int* dstA = ei + E;

    char* base = (char*)d_ws;
    size_t off = 0;
    auto alloc = [&](size_t bytes) -> void* {
        void* p = base + off;
        off += (bytes + 255) & ~(size_t)255;
        return p;
    };
    u16*   xbf    = (u16*)alloc((size_t)Nn * 128 * 2);
    u16*   xagg   = (u16*)alloc((size_t)Nn * 512 * 2);
    u16*   out1   = (u16*)alloc((size_t)Nn * 512 * 2);
    u16*   h2bf   = (u16*)alloc((size_t)Nn * 64 * 2);
    float* out2   = (float*)alloc((size_t)Nn * 64 * 4);
    u16*   W1t    = (u16*)alloc(512 * 128 * 2);
    u16*   W2t    = (u16*)alloc(64 * 512 * 2);
    float* Wa     = (float*)alloc(128 * 8 * 4);
    float* alS1   = (float*)alloc((size_t)Nn * 4 * 4);
    float* alD1   = (float*)alloc((size_t)Nn * 4 * 4);
    float* alS2   = (float*)alloc((size_t)Nn * 4);
    float* alD2   = (float*)alloc((size_t)Nn * 4);
    float* wE1    = (float*)alloc((size_t)Et * 4 * 4);
    float* wE2    = (float*)alloc((size_t)Et * 4);
    int*   deg    = (int*)alloc((size_t)2 * Nn * 4);
    int*   fill   = deg + Nn;
    int*   offs   = (int*)alloc((size_t)(Nn + 1) * 4);
    int*   bsum   = (int*)alloc(64 * 4);
    int*   sCSR   = (int*)alloc((size_t)Et * 4);
    int*   dCSR   = (int*)alloc((size_t)Et * 4);
    float* pooled = (float*)alloc((size_t)NG * 64 * 4);
    (void)ws_size; (void)n_in;

    const int EB = (Et + 255) / 256;
    const int NB = (Nn + 2047) / 2048;

    // ---- weight prep + fused x prep ----
    castw_kernel<<<(512 * 128 + 64 * 512 + 255) / 256, 256, 0, stream>>>(W1, W2, W1t, W2t);
    wa_kernel<<<4, 256, 0, stream>>>(W1, a_src1, a_dst1, Wa);
    prep_x<<<(Nn + 3) / 4, 256, 0, stream>>>(x, Wa, xbf, alS1, alD1, Nn);

    // ---- CSR build ----
    hipMemsetAsync(deg, 0, sizeof(int) * 2 * Nn, stream);
    count_kernel<<<EB, 256, 0, stream>>>(dstA, E, Nn, deg);
    scanA_kernel<<<NB, 256, 0, stream>>>(deg, offs, bsum, Nn);
    scanB_kernel<<<1, 64, 0, stream>>>(bsum, NB);
    scanC_kernel<<<(Nn + 255) / 256, 256, 0, stream>>>(offs, bsum, Nn);
    scatter_kernel<<<EB, 256, 0, stream>>>(srcA, dstA, E, Nn, offs, fill, sCSR, dCSR);

    // ---- layer 1 ----
    edgew1_kernel<<<EB, 256, 0, stream>>>(sCSR, dCSR, Et, alS1, alD1, wE1);
    aggx_kernel<<<Nn, 64, 0, stream>>>(xbf, sCSR, offs, wE1, xagg);
    dim3 g1((Nn + 127) / 128, 4);
    gemm1_mfma<<<g1, 256, 0, stream>>>(xagg, W1t, b1, out1, Nn);

    // ---- layer 2 (al2 fused into gemm2) ----
    gemm2_mfma<<<(Nn + 63) / 64, 256, 0, stream>>>(out1, W2t, a_src2, a_dst2,
                                                   h2bf, alS2, alD2, Nn);
    edgew2_kernel<<<EB, 256, 0, stream>>>(sCSR, dCSR, Et, alS2, alD2, wE2);
    agg2_kernel<<<(Nn + 3) / 4, 256, 0, stream>>>(h2bf, sCSR, offs, wE2, b2, out2, Nn);

    // ---- pool + head ----
    pool_kernel<<<NG, 64, 0, stream>>>(out2, batch, Nn, pooled);
    fc_kernel<<<NG, 64, 0, stream>>>(pooled, fcw1, fcb1, fcw2, fcb2, out);
}